// Round 5
// baseline (205.697 us; speedup 1.0000x reference)
//
#include <hip/hip_runtime.h>

// GRUCell fused kernel for MI355X (gfx950), round 5.
// B=65536, I=128, H=256, CAT=384. f16 MFMA 16x16x32.
// R4 -> R5: kernel was LDS-pipe-bound (~45us of ds_read_b128 per CU at the
// 32x64 wave tile). New shape: 4-wave block, wave tile 64x64 (wave owns all
// 64 rows x its 64 cols) -> B-fragments wave-unique, per-CU LDS reads drop
// 1.6x. 2 blocks/CU (LDS 80KB, launch_bounds(256,2)). Counted-vmcnt weight
// pipeline kept: 4 loads/chunk -> vmcnt(4) steady, vmcnt(0) at phase-2 tail.
// Rescale reads h_prev from global (L2-hot) instead of scalar LDS reads.

#define BATCH 65536
#define ISZ   128
#define HSZ   256
#define CAT   384
#define BM    64
#define NT    256
#define ROWB  768              // act row bytes (384 f16)
#define ACT_B (BM * ROWB)      // 49152
#define CH_B  16384            // one weight chunk: 256 rows x 64 B (K=32)

using half8   = __attribute__((ext_vector_type(8))) _Float16;
using floatx4 = __attribute__((ext_vector_type(4))) float;

typedef unsigned int u32;
typedef __attribute__((address_space(1))) const u32 gu32;
typedef __attribute__((address_space(3))) u32 lu32;

__device__ __forceinline__ void gload16(const void* g, void* l) {
    __builtin_amdgcn_global_load_lds((gu32*)g, (lu32*)l, 16, 0, 0);
}

#define BAR()      __builtin_amdgcn_s_barrier()
#define SCHED0()   __builtin_amdgcn_sched_barrier(0)
#define WAIT_VM4() asm volatile("s_waitcnt vmcnt(4)" ::: "memory")
#define WAIT_VM0() asm volatile("s_waitcnt vmcnt(0)" ::: "memory")
#define WAIT_LG0() asm volatile("s_waitcnt lgkmcnt(0)" ::: "memory")
#define MFMA       __builtin_amdgcn_mfma_f32_16x16x32_f16

__device__ __forceinline__ float hsig(float x) {
    return fminf(fmaxf(x * (1.0f / 6.0f) + 0.5f, 0.0f), 1.0f);
}
__device__ __forceinline__ float htanh(float x) {
    return fminf(fmaxf(x, -1.0f), 1.0f);
}
__device__ __forceinline__ half8 cvt8(float4 v0, float4 v1) {
    half8 h;
    h[0] = (_Float16)v0.x; h[1] = (_Float16)v0.y;
    h[2] = (_Float16)v0.z; h[3] = (_Float16)v0.w;
    h[4] = (_Float16)v1.x; h[5] = (_Float16)v1.y;
    h[6] = (_Float16)v1.z; h[7] = (_Float16)v1.w;
    return h;
}

// ---- weight prep: f32 [256x384] row-major -> f16 same layout in d_ws ----
// ws layout: Wz rows 0..255, Wr 256..511, Wh 512..767
__global__ __launch_bounds__(256) void prep_weights(
    const float* __restrict__ Wz, const float* __restrict__ Wr,
    const float* __restrict__ Wh, _Float16* __restrict__ ws)
{
    const int m = blockIdx.y;
    const float* src = (m == 0) ? Wz : (m == 1) ? Wr : Wh;
    _Float16* dst = ws + (size_t)m * (HSZ * CAT);
    const int base = (blockIdx.x * 256 + threadIdx.x) * 8;
    float4 v0 = *(const float4*)(src + base);
    float4 v1 = *(const float4*)(src + base + 4);
    *(half8*)(dst + base) = cvt8(v0, v1);
}

// chunk c: c<24 -> matrix (c&1 ? Wr : Wz), k-slice c>>1 ; c>=24 -> Wh, slice c-24.
// wbuf row n (64B): phys 16B slot p holds logical slot p ^ ((n>>1)&3).
// 4 waves -> 4 wave-loads each (i = w*4+ii covers rows i*16 + (lane>>2)).
__device__ __forceinline__ void issue_chunk(const _Float16* __restrict__ wf,
                                            unsigned char* wbuf, int c,
                                            int w, int lane) {
    const _Float16* src = (c < 24) ? (wf + (c & 1) * (HSZ * CAT))
                                   : (wf + 2 * (HSZ * CAT));
    const int kk = (c < 24) ? (c >> 1) : (c - 24);
    unsigned char* dst = wbuf + (c & 1) * CH_B;
    #pragma unroll
    for (int ii = 0; ii < 4; ++ii) {
        const int i = w * 4 + ii;                  // wave-load 0..15
        const int n = i * 16 + (lane >> 2);        // weight row 0..255
        const int ss = (lane & 3) ^ ((n >> 1) & 3);
        gload16(src + n * CAT + kk * 32 + ss * 8, dst + i * 1024);
    }
}

// swizzled read of the 16B B-fragment for weight row n, k-slot lk
__device__ __forceinline__ half8 wread(const unsigned char* buf, int n, int lk) {
    return *(const half8*)(buf + n * 64 + ((lk ^ ((n >> 1) & 3)) << 4));
}

__global__ __launch_bounds__(NT, 2) void gru_kernel(
    const float* __restrict__ x, const float* __restrict__ h_prev,
    const float* __restrict__ b_z, const float* __restrict__ b_r,
    const float* __restrict__ b_h, const _Float16* __restrict__ wf,
    float* __restrict__ out)
{
    __shared__ __align__(16) unsigned char lds[ACT_B + 2 * CH_B];  // 80 KiB
    unsigned char* const act  = lds;
    unsigned char* const wbuf = lds + ACT_B;

    const int t    = threadIdx.x;
    const int lane = t & 63;
    const int w    = t >> 6;        // wave 0..3: cols w*64 .. +63, all 64 rows
    const int lr   = lane & 15;
    const int lk   = lane >> 4;
    const int row0 = blockIdx.x * BM;

    // prefetch first two weight chunks (z0 -> buf0, r0 -> buf1)
    issue_chunk(wf, wbuf, 0, w, lane);
    issue_chunk(wf, wbuf, 1, w, lane);

    // biases folded into accumulator init; b_h held for phase 2
    float bhv[4];
    floatx4 accz[4][4], accr[4][4];
    #pragma unroll
    for (int j = 0; j < 4; ++j) {
        const int col = w * 64 + j * 16 + lr;
        const float vz = b_z[col];
        const float vr = b_r[col];
        bhv[j] = b_h[col];
        floatx4 tz = {vz, vz, vz, vz};
        floatx4 tr = {vr, vr, vr, vr};
        #pragma unroll
        for (int f = 0; f < 4; ++f) { accz[f][j] = tz; accr[f][j] = tr; }
    }

    // ---- stage act: x (64x128) + h (64x256), f32 -> f16, row-XOR swizzled ----
    for (int c = t; c < BM * 16; c += NT) {
        int row = c >> 4, kc = c & 15;
        const float* g = x + (size_t)(row0 + row) * ISZ + kc * 8;
        float4 v0 = *(const float4*)g;
        float4 v1 = *(const float4*)(g + 4);
        *(half8*)(act + row * ROWB + ((kc * 16) ^ ((row & 7) << 4))) = cvt8(v0, v1);
    }
    for (int c = t; c < BM * 32; c += NT) {
        int row = c >> 5, kc = c & 31;
        const float* g = h_prev + (size_t)(row0 + row) * HSZ + kc * 8;
        float4 v0 = *(const float4*)g;
        float4 v1 = *(const float4*)(g + 4);
        *(half8*)(act + row * ROWB + ((256 + kc * 16) ^ ((row & 7) << 4))) = cvt8(v0, v1);
    }
    WAIT_VM0(); WAIT_LG0(); SCHED0();
    BAR();   // act + chunks 0,1 resident for all waves

    half8 a[4];   // A-fragments: rows f*16+lr, shared across waves via LDS

    // ---- phase 1: z,r pre-activations; per kk: z-chunk (buf0), r-chunk (buf1)
    // Ledger (4 loads/chunk/wave): at each sub-chunk top 8 outstanding;
    // vmcnt(4) retires exactly the chunk about to be consumed.
    #pragma unroll 1
    for (int kk = 0; kk < 12; ++kk) {
        // --- z sub-chunk ---
        WAIT_VM4(); SCHED0(); BAR();
        #pragma unroll
        for (int f = 0; f < 4; ++f) {
            const int row = f * 16 + lr;
            a[f] = *(const half8*)(act + row * ROWB +
                                   ((kk * 64 + lk * 16) ^ ((row & 7) << 4)));
        }
        __builtin_amdgcn_s_setprio(1);
        #pragma unroll
        for (int j = 0; j < 4; ++j) {
            half8 bf = wread(wbuf, w * 64 + j * 16 + lr, lk);
            #pragma unroll
            for (int f = 0; f < 4; ++f)
                accz[f][j] = MFMA(a[f], bf, accz[f][j], 0, 0, 0);
        }
        __builtin_amdgcn_s_setprio(0);
        WAIT_LG0(); SCHED0(); BAR();
        issue_chunk(wf, wbuf, 2 * kk + 2, w, lane);   // z_{kk+1} (h0 at kk=11)
        // --- r sub-chunk (A-frags reused) ---
        WAIT_VM4(); SCHED0(); BAR();
        __builtin_amdgcn_s_setprio(1);
        #pragma unroll
        for (int j = 0; j < 4; ++j) {
            half8 bf = wread(wbuf + CH_B, w * 64 + j * 16 + lr, lk);
            #pragma unroll
            for (int f = 0; f < 4; ++f)
                accr[f][j] = MFMA(a[f], bf, accr[f][j], 0, 0, 0);
        }
        __builtin_amdgcn_s_setprio(0);
        WAIT_LG0(); SCHED0(); BAR();
        issue_chunk(wf, wbuf, 2 * kk + 3, w, lane);   // r_{kk+1} (h1 at kk=11)
    }

    // ---- rescale: z = hsig(acc); r*h (h from global, L2-hot) -> act h-region
    // (h0,h1 weight loads in flight; their value-uses below force no waits --
    // the compiler only waits for the h_prev loads, which are younger.)
    #pragma unroll
    for (int f = 0; f < 4; ++f) {
        #pragma unroll
        for (int j = 0; j < 4; ++j) {
            #pragma unroll
            for (int q = 0; q < 4; ++q) {
                const int row = f * 16 + lk * 4 + q;    // C/D row=(l>>4)*4+q
                const int col = w * 64 + j * 16 + lr;   //     col=l&15
                accz[f][j][q] = hsig(accz[f][j][q]);    // bias pre-added
                float rr = hsig(accr[f][j][q]);
                float hv = h_prev[(size_t)(row0 + row) * HSZ + col];
                *(_Float16*)(act + row * ROWB +
                             ((256 + col * 2) ^ ((row & 7) << 4))) =
                    (_Float16)(rr * hv);
            }
        }
    }
    WAIT_LG0();   // own rescale writes landed; next barrier publishes to all

    // ---- phase 2: h_tilde pre-activation, chunks 24..35 in alternating bufs
    floatx4 acch[4][4];
    #pragma unroll
    for (int j = 0; j < 4; ++j) {
        floatx4 th = {bhv[j], bhv[j], bhv[j], bhv[j]};
        #pragma unroll
        for (int f = 0; f < 4; ++f) acch[f][j] = th;
    }
    #pragma unroll 1
    for (int kk = 0; kk < 12; ++kk) {
        // Tail: at kk=11 the only outstanding loads ARE chunk 35 -- vmcnt(4)
        // would pass without waiting. Drain fully (R4 lesson).
        if (kk < 11) { WAIT_VM4(); } else { WAIT_VM0(); }
        SCHED0(); BAR();
        const unsigned char* buf = wbuf + (kk & 1) * CH_B;
        #pragma unroll
        for (int f = 0; f < 4; ++f) {
            const int row = f * 16 + lr;
            a[f] = *(const half8*)(act + row * ROWB +
                                   ((kk * 64 + lk * 16) ^ ((row & 7) << 4)));
        }
        __builtin_amdgcn_s_setprio(1);
        #pragma unroll
        for (int j = 0; j < 4; ++j) {
            half8 bf = wread(buf, w * 64 + j * 16 + lr, lk);
            #pragma unroll
            for (int f = 0; f < 4; ++f)
                acch[f][j] = MFMA(a[f], bf, acch[f][j], 0, 0, 0);
        }
        __builtin_amdgcn_s_setprio(0);
        WAIT_LG0(); SCHED0(); BAR();
        if (kk < 10) issue_chunk(wf, wbuf, 26 + kk, w, lane);
    }

    // ---- epilogue: h_next = z*h + (1-z)*hardtanh(.) ----
    #pragma unroll
    for (int f = 0; f < 4; ++f) {
        #pragma unroll
        for (int j = 0; j < 4; ++j) {
            #pragma unroll
            for (int q = 0; q < 4; ++q) {
                const int row = f * 16 + lk * 4 + q;
                const int col = w * 64 + j * 16 + lr;
                float ht = htanh(acch[f][j][q]);        // bias pre-added
                float zz = accz[f][j][q];
                float hv = h_prev[(size_t)(row0 + row) * HSZ + col];
                out[(size_t)(row0 + row) * HSZ + col] = zz * hv + (1.0f - zz) * ht;
            }
        }
    }
}

extern "C" void kernel_launch(void* const* d_in, const int* in_sizes, int n_in,
                              void* d_out, int out_size, void* d_ws, size_t ws_size,
                              hipStream_t stream) {
    const float* x  = (const float*)d_in[0];
    const float* h  = (const float*)d_in[1];
    const float* Wz = (const float*)d_in[2];
    const float* bz = (const float*)d_in[3];
    const float* Wr = (const float*)d_in[4];
    const float* br = (const float*)d_in[5];
    const float* Wh = (const float*)d_in[6];
    const float* bh = (const float*)d_in[7];
    _Float16* wf = (_Float16*)d_ws;   // 3*256*384*2 = 576 KiB scratch

    prep_weights<<<dim3(48, 3), 256, 0, stream>>>(Wz, Wr, Wh, wf);
    gru_kernel<<<dim3(BATCH / BM), NT, 0, stream>>>(
        x, h, bz, br, bh, wf, (float*)d_out);
}